// Round 2
// baseline (2869.364 us; speedup 1.0000x reference)
//
#include <hip/hip_runtime.h>
#include <cfloat>

// Problem constants (fixed by setup_inputs)
#define BATCH 4
#define DIMC 1792            // descriptor dim
#define HWSZ 3136            // 56*56 spatial
#define NPROT 3136           // prototypes
#define MROWS (BATCH*HWSZ)   // 12544
#define NPT 49               // NPROT/64 prototype tiles

// ws layout (floats):
//   P2   [DIMC][MROWS]      22,478,848
//   phiT [DIMC][MROWS]      22,478,848
//   WT   [DIMC][DIMC]        3,211,264
//   cn   [NPROT]                 3,136
//   rn   [MROWS]                12,544
//   ptop [MROWS][NPT][3]     1,843,968
// total ~200.1 MB

__device__ __forceinline__ void ins3(float v, float& t0, float& t1, float& t2) {
    if (v < t2) {
        if (v < t1) {
            t2 = t1;
            if (v < t0) { t1 = t0; t0 = v; }
            else        { t1 = v; }
        } else {
            t2 = v;
        }
    }
}

// ---- pack p[b][c][hw] -> P2[c][b*HWSZ+hw] (row stride MROWS) --------------
__global__ void pack_p_kernel(const float* __restrict__ p, float* __restrict__ P2) {
    int idx = blockIdx.x * 256 + threadIdx.x;   // over (c, b, hw4)
    // total = DIMC*BATCH*(HWSZ/4) = 1792*4*784
    int hw4 = idx % (HWSZ / 4);
    int tmp = idx / (HWSZ / 4);
    int b   = tmp % BATCH;
    int c   = tmp / BATCH;
    if (c >= DIMC) return;
    float4 v = *(const float4*)(p + ((size_t)(b * DIMC + c)) * HWSZ + hw4 * 4);
    *(float4*)(P2 + (size_t)c * MROWS + b * HWSZ + hw4 * 4) = v;
}

// ---- WT[c][d] = W[d][c] ----------------------------------------------------
__global__ void transpose_w_kernel(const float* __restrict__ W, float* __restrict__ WT) {
    __shared__ float tile[32][33];
    int bx = blockIdx.x * 32, by = blockIdx.y * 32;
    int tx = threadIdx.x, ty = threadIdx.y;       // (32,8)
#pragma unroll
    for (int j = 0; j < 32; j += 8)
        tile[ty + j][tx] = W[(size_t)(by + ty + j) * DIMC + bx + tx];
    __syncthreads();
#pragma unroll
    for (int j = 0; j < 32; j += 8)
        WT[(size_t)(bx + ty + j) * DIMC + by + tx] = tile[tx][ty + j];
}

// ---- cn[j] += partial column norms of C -----------------------------------
__global__ void cn_kernel(const float* __restrict__ C, float* __restrict__ cn) {
    int j  = blockIdx.x * 256 + threadIdx.x;
    int d0 = blockIdx.y * 128;
    if (j >= NPROT) return;
    float s = 0.f;
    for (int d = d0; d < d0 + 128; ++d) {
        float v = C[(size_t)d * NPROT + j];
        s += v * v;
    }
    atomicAdd(&cn[j], s);
}

// ---- rn[r] += partial row norms of phi (phiT layout) ----------------------
__global__ void rn_kernel(const float* __restrict__ phiT, float* __restrict__ rn) {
    int r  = blockIdx.x * 256 + threadIdx.x;   // exact: MROWS/256 = 49
    int d0 = blockIdx.y * 128;
    float s = 0.f;
    for (int d = d0; d < d0 + 128; ++d) {
        float v = phiT[(size_t)d * MROWS + r];
        s += v * v;
    }
    atomicAdd(&rn[r], s);
}

// ---- GEMM1: phiT[d][r] = sum_c WT[c][d] * P2[c][r] + bias[d] ---------------
// 128(d) x 128(r) tile, BK=8, 256 threads, 8x8 microtile
__global__ __launch_bounds__(256) void gemm1_kernel(
    const float* __restrict__ P2, const float* __restrict__ WT,
    const float* __restrict__ bias, float* __restrict__ phiT) {
    __shared__ float Aw[8][128];   // [k][d]
    __shared__ float Bp[8][128];   // [k][r]
    const int tid = threadIdx.x;
    const int r0 = blockIdx.x * 128;   // MROWS/128 = 98
    const int d0 = blockIdx.y * 128;   // DIMC/128 = 14
    const int lk = tid >> 5;           // 0..7
    const int l4 = (tid & 31) * 4;     // 0..124
    const int tx = tid & 15;           // r-dir
    const int ty = tid >> 4;           // d-dir

    float acc[8][8] = {};
    for (int c0 = 0; c0 < DIMC; c0 += 8) {
        float4 av = *(const float4*)(WT + (size_t)(c0 + lk) * DIMC + d0 + l4);
        float4 bv = *(const float4*)(P2 + (size_t)(c0 + lk) * MROWS + r0 + l4);
        *(float4*)&Aw[lk][l4] = av;
        *(float4*)&Bp[lk][l4] = bv;
        __syncthreads();
#pragma unroll
        for (int k = 0; k < 8; ++k) {
            float4 a0 = *(const float4*)&Aw[k][ty * 4];
            float4 a1 = *(const float4*)&Aw[k][ty * 4 + 64];
            float4 b0 = *(const float4*)&Bp[k][tx * 4];
            float4 b1 = *(const float4*)&Bp[k][tx * 4 + 64];
            float a[8] = {a0.x, a0.y, a0.z, a0.w, a1.x, a1.y, a1.z, a1.w};
            float b[8] = {b0.x, b0.y, b0.z, b0.w, b1.x, b1.y, b1.z, b1.w};
#pragma unroll
            for (int i = 0; i < 8; ++i)
#pragma unroll
                for (int j = 0; j < 8; ++j)
                    acc[i][j] += a[i] * b[j];
        }
        __syncthreads();
    }
#pragma unroll
    for (int i = 0; i < 8; ++i) {
        int d = d0 + ty * 4 + ((i < 4) ? i : 64 + (i - 4));
        float bs = bias[d];
        float4 o0 = make_float4(acc[i][0] + bs, acc[i][1] + bs, acc[i][2] + bs, acc[i][3] + bs);
        float4 o1 = make_float4(acc[i][4] + bs, acc[i][5] + bs, acc[i][6] + bs, acc[i][7] + bs);
        *(float4*)(phiT + (size_t)d * MROWS + r0 + tx * 4) = o0;
        *(float4*)(phiT + (size_t)d * MROWS + r0 + tx * 4 + 64) = o1;
    }
}

// ---- GEMM2 + top-3: 256(r) x 64(p) tile per block, one p-tile each ---------
// t[r][j] = cn[j] - 2 * sum_c phiT[c][r] * C[c][j];  keep 3 smallest per row.
__global__ __launch_bounds__(256) void gemm2_kernel(
    const float* __restrict__ phiT, const float* __restrict__ C,
    const float* __restrict__ cn, float* __restrict__ ptop) {
    __shared__ float As[8][256];   // [k][m]
    __shared__ float Bs[8][64];    // [k][j]
    __shared__ float red[256][8][3];
    const int tid = threadIdx.x;

    // bijective XCD chunking over 2401 blocks (q=300, rem=1):
    int bid = blockIdx.x;
    int xcd = bid & 7, idx = bid >> 3;
    int linear = (xcd == 0) ? idx : (301 + (xcd - 1) * 300 + idx);
    const int mbase = (linear / NPT) * 256;   // row-tile base
    const int pt    = linear % NPT;           // prototype tile
    const int p0    = pt * 64;

    const int lk  = tid >> 5;         // 0..7
    const int lm4 = (tid & 31) * 4;   // 0..124 (A, plus +128)
    const int lj2 = (tid & 31) * 2;   // 0..62  (B)
    const int tm = tid & 31;          // m-dir
    const int tn = tid >> 5;          // n-dir

    float acc[8][8] = {};
    for (int c0 = 0; c0 < DIMC; c0 += 8) {
        float4 a0v = *(const float4*)(phiT + (size_t)(c0 + lk) * MROWS + mbase + lm4);
        float4 a1v = *(const float4*)(phiT + (size_t)(c0 + lk) * MROWS + mbase + lm4 + 128);
        float2 bv  = *(const float2*)(C + (size_t)(c0 + lk) * NPROT + p0 + lj2);
        *(float4*)&As[lk][lm4] = a0v;
        *(float4*)&As[lk][lm4 + 128] = a1v;
        *(float2*)&Bs[lk][lj2] = bv;
        __syncthreads();
#pragma unroll
        for (int k = 0; k < 8; ++k) {
            float4 a0 = *(const float4*)&As[k][tm * 4];
            float4 a1 = *(const float4*)&As[k][tm * 4 + 128];
            float4 b0 = *(const float4*)&Bs[k][tn * 4];
            float4 b1 = *(const float4*)&Bs[k][tn * 4 + 32];
            float a[8] = {a0.x, a0.y, a0.z, a0.w, a1.x, a1.y, a1.z, a1.w};
            float b[8] = {b0.x, b0.y, b0.z, b0.w, b1.x, b1.y, b1.z, b1.w};
#pragma unroll
            for (int i = 0; i < 8; ++i)
#pragma unroll
                for (int j = 0; j < 8; ++j)
                    acc[i][j] += a[i] * b[j];
        }
        __syncthreads();
    }
    // epilogue: t = cn - 2*fc, per-row top3, reduce across tn
    float cnv[8];
#pragma unroll
    for (int j = 0; j < 8; ++j) {
        int col = tn * 4 + ((j < 4) ? j : 32 + (j - 4));
        cnv[j] = cn[p0 + col];
    }
#pragma unroll
    for (int i = 0; i < 8; ++i) {
        float t0 = FLT_MAX, t1 = FLT_MAX, t2 = FLT_MAX;
#pragma unroll
        for (int j = 0; j < 8; ++j)
            ins3(cnv[j] - 2.f * acc[i][j], t0, t1, t2);
        int row = tm * 4 + ((i < 4) ? i : 128 + (i - 4));
        red[row][tn][0] = t0;
        red[row][tn][1] = t1;
        red[row][tn][2] = t2;
    }
    __syncthreads();
    {
        int row = tid;  // 0..255
        float m0 = FLT_MAX, m1 = FLT_MAX, m2 = FLT_MAX;
#pragma unroll
        for (int s = 0; s < 8; ++s) {
            ins3(red[row][s][0], m0, m1, m2);
            ins3(red[row][s][1], m0, m1, m2);
            ins3(red[row][s][2], m0, m1, m2);
        }
        size_t base = ((size_t)(mbase + row) * NPT + pt) * 3;
        ptop[base + 0] = m0;
        ptop[base + 1] = m1;
        ptop[base + 2] = m2;
    }
}

// ---- final merge + sqrt + softmin score ------------------------------------
__global__ void final_kernel(const float* __restrict__ ptop,
                             const float* __restrict__ rn,
                             float* __restrict__ out) {
    int r = blockIdx.x * 256 + threadIdx.x;   // exact: MROWS/256 = 49
    float t0 = FLT_MAX, t1 = FLT_MAX, t2 = FLT_MAX;
    const float* pp = ptop + (size_t)r * NPT * 3;
    for (int q = 0; q < NPT * 3; ++q) ins3(pp[q], t0, t1, t2);
    float rv = rn[r];
    float d0 = sqrtf(rv + t0);
    float d1 = sqrtf(rv + t1);
    float d2 = sqrtf(rv + t2);
    float w0 = 1.f / (1.f + expf(d0 - d1) + expf(d0 - d2));
    out[r] = w0 * d0;
}

extern "C" void kernel_launch(void* const* d_in, const int* in_sizes, int n_in,
                              void* d_out, int out_size, void* d_ws, size_t ws_size,
                              hipStream_t stream) {
    const float* p    = (const float*)d_in[0];
    const float* W    = (const float*)d_in[1];
    const float* bias = (const float*)d_in[2];
    const float* C    = (const float*)d_in[3];
    float* out = (float*)d_out;

    float* ws   = (float*)d_ws;
    float* P2   = ws;
    float* phiT = P2 + (size_t)DIMC * MROWS;
    float* WT   = phiT + (size_t)DIMC * MROWS;
    float* cn   = WT + (size_t)DIMC * DIMC;
    float* rn   = cn + NPROT;
    float* ptop = rn + MROWS;

    // zero the atomic accumulators (cn and rn are adjacent)
    hipMemsetAsync(cn, 0, (NPROT + MROWS) * sizeof(float), stream);

    {
        int total4 = DIMC * BATCH * (HWSZ / 4);
        pack_p_kernel<<<(total4 + 255) / 256, 256, 0, stream>>>(p, P2);
    }
    transpose_w_kernel<<<dim3(DIMC / 32, DIMC / 32), dim3(32, 8), 0, stream>>>(W, WT);
    cn_kernel<<<dim3((NPROT + 255) / 256, DIMC / 128), 256, 0, stream>>>(C, cn);
    gemm1_kernel<<<dim3(MROWS / 128, DIMC / 128), 256, 0, stream>>>(P2, WT, bias, phiT);
    rn_kernel<<<dim3(MROWS / 256, DIMC / 128), 256, 0, stream>>>(phiT, rn);
    gemm2_kernel<<<(MROWS / 256) * NPT, 256, 0, stream>>>(phiT, C, cn, ptop);
    final_kernel<<<MROWS / 256, 256, 0, stream>>>(ptop, rn, out);
}

// Round 4
// 647.557 us; speedup vs baseline: 4.4311x; 4.4311x over previous
//
#include <hip/hip_runtime.h>
#include <hip/hip_bf16.h>
#include <cfloat>

#define BATCH 4
#define DIMC 1792
#define HWSZ 3136
#define NPROT 3136
#define NPAD 3200           // NPROT padded to a multiple of 128
#define MROWS 12544

typedef unsigned short u16;
typedef unsigned int u32;
using bf16x8 = __attribute__((ext_vector_type(8))) short;
using f32x4  = __attribute__((ext_vector_type(4))) float;

__device__ __forceinline__ float bf2f(u32 u) { return __uint_as_float(u << 16); }
__device__ __forceinline__ u16 f2bf(float x) {
    __hip_bfloat16 h = __float2bfloat16(x);   // RNE
    return *reinterpret_cast<u16*>(&h);
}

// async global->LDS, 16B per lane; LDS dest = wave-uniform base + lane*16
__device__ __forceinline__ void gload_lds16(const u16* g, u16* l) {
    __builtin_amdgcn_global_load_lds(
        (const __attribute__((address_space(1))) void*)g,
        (__attribute__((address_space(3))) void*)l, 16, 0, 0);
}

__device__ __forceinline__ void ins3(float v, float& t0, float& t1, float& t2) {
    if (v < t2) {
        if (v < t1) {
            t2 = t1;
            if (v < t0) { t1 = t0; t0 = v; }
            else        { t1 = v; }
        } else {
            t2 = v;
        }
    }
}

// ---- pack p[b][c][hw] (fp32) -> Pbf[r=b*HWSZ+hw][c] (bf16) ----------------
__global__ void pack_p_kernel(const float* __restrict__ p, u16* __restrict__ Pbf) {
    __shared__ float tile[32][33];
    int hw0 = blockIdx.x * 32, c0 = blockIdx.y * 32, b = blockIdx.z;
    int tx = threadIdx.x, ty = threadIdx.y;   // (32,8)
#pragma unroll
    for (int j = 0; j < 32; j += 8)
        tile[ty + j][tx] = p[((size_t)(b * DIMC + c0 + ty + j)) * HWSZ + hw0 + tx];
    __syncthreads();
#pragma unroll
    for (int j = 0; j < 32; j += 8) {
        int r = b * HWSZ + hw0 + ty + j;
        Pbf[(size_t)r * DIMC + c0 + tx] = f2bf(tile[tx][ty + j]);
    }
}

// ---- cast W[d][c] fp32 -> Wbf[d][c] bf16 ----------------------------------
__global__ void pack_w_kernel(const float* __restrict__ W, u16* __restrict__ Wbf) {
    size_t i = (size_t)(blockIdx.x * 256 + threadIdx.x) * 4;   // exact grid
    float4 v = *(const float4*)(W + i);
    ushort4 o;
    o.x = f2bf(v.x); o.y = f2bf(v.y); o.z = f2bf(v.z); o.w = f2bf(v.w);
    *(ushort4*)(Wbf + i) = o;
}

// ---- pack C[d][j] fp32 -> CTbf[j][d] bf16 ---------------------------------
__global__ void pack_c_kernel(const float* __restrict__ C, u16* __restrict__ CTbf) {
    __shared__ float tile[32][33];
    int j0 = blockIdx.x * 32, d0 = blockIdx.y * 32;
    int tx = threadIdx.x, ty = threadIdx.y;   // (32,8)
#pragma unroll
    for (int jj = 0; jj < 32; jj += 8)
        tile[ty + jj][tx] = C[(size_t)(d0 + ty + jj) * NPROT + j0 + tx];
    __syncthreads();
#pragma unroll
    for (int jj = 0; jj < 32; jj += 8)
        CTbf[(size_t)(j0 + ty + jj) * DIMC + d0 + tx] = f2bf(tile[tx][ty + jj]);
}

// ---- cn[j] += partial column norms of C (fp32 source) ---------------------
__global__ void cn_kernel(const float* __restrict__ C, float* __restrict__ cn) {
    int j  = blockIdx.x * 256 + threadIdx.x;
    int d0 = blockIdx.y * 128;
    if (j >= NPROT) return;
    float s = 0.f;
    for (int d = d0; d < d0 + 128; ++d) {
        float v = C[(size_t)d * NPROT + j];
        s += v * v;
    }
    atomicAdd(&cn[j], s);
}

// ---- MFMA GEMM: out[r][n] = sum_k A[r][k]*B[n][k] (+bias[n]), bf16 out ----
// 128x128 tile, 4 waves (each 64x64 = 4x4 frags of 16x16x32), BK=32,
// global_load_lds width-16 staging (m97 structure), 2 barriers per K-step.
// LDS layout per tile: [row][32 k-elems], row-major 64B rows; wave w's 32
// rows occupy bytes [w*2048, (w+1)*2048) == wave base + lane*16 (linear).
template<bool BIAS>
__global__ __launch_bounds__(256) void gemm_kernel(
    const u16* __restrict__ A,    // [M][DIMC] bf16
    const u16* __restrict__ B,    // [N][DIMC] bf16 (B^T layout, K contiguous)
    const float* __restrict__ bias,
    u16* __restrict__ out, int ldo)
{
    __shared__ __align__(16) u16 Als[128 * 32];
    __shared__ __align__(16) u16 Bls[128 * 32];
    const int tid  = threadIdx.x;
    const int wid  = tid >> 6;
    const int lane = tid & 63;
    const int r0 = blockIdx.x * 128;
    const int n0 = blockIdx.y * 128;

    // staging: wave w covers rows [w*32, w*32+32) of the A-tile and B-tile.
    // lane -> (row = w*32 + (lane>>2) [+16], seg = (lane&3)*8 elems)
    const int srow = lane >> 2;
    const int sseg = (lane & 3) * 8;
    const u16* Ag = A + (size_t)(r0 + wid * 32 + srow) * DIMC + sseg;
    const u16* Bg = B + (size_t)(n0 + wid * 32 + srow) * DIMC + sseg;
    u16* AlsW = Als + wid * 1024;   // wave-uniform LDS base (bytes: wid*2048)
    u16* BlsW = Bls + wid * 1024;

    // compute mapping: wave (wm,wn) quadrant, 16x16x32 fragments
    const int wm = (wid >> 1) * 64;
    const int wn = (wid & 1) * 64;
    const int lrow = lane & 15;
    const int kseg = (lane >> 4) * 8;
    const int rsub = (lane >> 4) * 4;

    f32x4 acc[4][4];
#pragma unroll
    for (int m = 0; m < 4; ++m)
#pragma unroll
        for (int n = 0; n < 4; ++n)
            acc[m][n] = (f32x4){0.f, 0.f, 0.f, 0.f};

    for (int k0 = 0; k0 < DIMC; k0 += 32) {
        gload_lds16(Ag + k0,                      AlsW);
        gload_lds16(Ag + (size_t)16 * DIMC + k0,  AlsW + 512);
        gload_lds16(Bg + k0,                      BlsW);
        gload_lds16(Bg + (size_t)16 * DIMC + k0,  BlsW + 512);
        __syncthreads();   // drains vmcnt(0): LDS tile complete
        bf16x8 af[4], bv[4];
#pragma unroll
        for (int m = 0; m < 4; ++m)
            af[m] = *(const bf16x8*)(Als + (wm + m * 16 + lrow) * 32 + kseg);
#pragma unroll
        for (int n = 0; n < 4; ++n)
            bv[n] = *(const bf16x8*)(Bls + (wn + n * 16 + lrow) * 32 + kseg);
#pragma unroll
        for (int m = 0; m < 4; ++m)
#pragma unroll
            for (int n = 0; n < 4; ++n)
                acc[m][n] = __builtin_amdgcn_mfma_f32_16x16x32_bf16(
                    af[m], bv[n], acc[m][n], 0, 0, 0);
        __syncthreads();
    }

    // epilogue: C/D layout col=lane&15, row=(lane>>4)*4+i  [m89-verified]
#pragma unroll
    for (int n = 0; n < 4; ++n) {
        int col = n0 + wn + n * 16 + lrow;
        float bs = 0.f;
        if (BIAS) bs = bias[col];
#pragma unroll
        for (int m = 0; m < 4; ++m) {
            f32x4 v = acc[m][n];
#pragma unroll
            for (int i = 0; i < 4; ++i) {
                int row = r0 + wm + m * 16 + rsub + i;
                out[(size_t)row * ldo + col] = f2bf(v[i] + bs);
            }
        }
    }
}

// ---- rn[r] = sum_d phibf[r][d]^2 (wave per row) ---------------------------
__global__ void rn_kernel(const u16* __restrict__ phibf, float* __restrict__ rn) {
    int row  = blockIdx.x * 4 + (threadIdx.x >> 6);
    int lane = threadIdx.x & 63;
    const u16* pr = phibf + (size_t)row * DIMC;
    float s = 0.f;
#pragma unroll
    for (int it = 0; it < 7; ++it) {
        uint2 v = *(const uint2*)(pr + (it * 64 + lane) * 4);
        float f0 = bf2f(v.x & 0xffffu), f1 = bf2f(v.x >> 16);
        float f2 = bf2f(v.y & 0xffffu), f3 = bf2f(v.y >> 16);
        s += f0 * f0 + f1 * f1 + f2 * f2 + f3 * f3;
    }
#pragma unroll
    for (int off = 32; off > 0; off >>= 1) s += __shfl_down(s, off);
    if (lane == 0) rn[row] = s;
}

// ---- top-3 + sqrt + softmin score (wave per row) --------------------------
__global__ void top3_final_kernel(const u16* __restrict__ fc,
                                  const float* __restrict__ cn,
                                  const float* __restrict__ rn,
                                  float* __restrict__ out) {
    int row  = blockIdx.x * 4 + (threadIdx.x >> 6);
    int lane = threadIdx.x & 63;
    const u16* fr = fc + (size_t)row * NPAD;
    float t0 = FLT_MAX, t1 = FLT_MAX, t2 = FLT_MAX;
#pragma unroll
    for (int it = 0; it < 6; ++it) {        // 6*512 = 3072 prototypes
        int j0 = (it * 64 + lane) * 8;
        uint4 v = *(const uint4*)(fr + j0);
        u32 wd[4] = {v.x, v.y, v.z, v.w};
#pragma unroll
        for (int e = 0; e < 4; ++e) {
            float flo = bf2f(wd[e] & 0xffffu);
            float fhi = bf2f(wd[e] >> 16);
            ins3(cn[j0 + 2 * e]     - 2.f * flo, t0, t1, t2);
            ins3(cn[j0 + 2 * e + 1] - 2.f * fhi, t0, t1, t2);
        }
    }
    {   // tail: prototypes 3072..3135
        int j = 3072 + lane;
        ins3(cn[j] - 2.f * bf2f((u32)fr[j]), t0, t1, t2);
    }
#pragma unroll
    for (int off = 32; off > 0; off >>= 1) {
        float s0 = __shfl_xor(t0, off);
        float s1 = __shfl_xor(t1, off);
        float s2 = __shfl_xor(t2, off);
        ins3(s0, t0, t1, t2);
        ins3(s1, t0, t1, t2);
        ins3(s2, t0, t1, t2);
    }
    if (lane == 0) {
        float rv = rn[row];
        float d0 = sqrtf(rv + t0), d1 = sqrtf(rv + t1), d2 = sqrtf(rv + t2);
        float w0 = 1.f / (1.f + expf(d0 - d1) + expf(d0 - d2));
        out[row] = w0 * d0;
    }
}

extern "C" void kernel_launch(void* const* d_in, const int* in_sizes, int n_in,
                              void* d_out, int out_size, void* d_ws, size_t ws_size,
                              hipStream_t stream) {
    const float* p    = (const float*)d_in[0];
    const float* W    = (const float*)d_in[1];
    const float* bias = (const float*)d_in[2];
    const float* C    = (const float*)d_in[3];
    float* out = (float*)d_out;

    char* w = (char*)d_ws;
    u16* Pbf   = (u16*)w;  w += (size_t)MROWS * DIMC * 2;   // 45.0 MB
    u16* Wbf   = (u16*)w;  w += (size_t)DIMC * DIMC * 2;    //  6.4 MB
    u16* CTbf  = (u16*)w;  w += (size_t)NPAD * DIMC * 2;    // 11.5 MB
    u16* phibf = (u16*)w;  w += (size_t)MROWS * DIMC * 2;   // 45.0 MB
    u16* fc    = (u16*)w;  w += (size_t)MROWS * NPAD * 2;   // 80.3 MB
    float* cn  = (float*)w; w += (size_t)NPROT * 4;
    float* rn  = (float*)w;                                  // total ~188.2 MB

    hipMemsetAsync(cn, 0, NPROT * sizeof(float), stream);

    pack_p_kernel<<<dim3(HWSZ / 32, DIMC / 32, BATCH), dim3(32, 8), 0, stream>>>(p, Pbf);
    pack_w_kernel<<<(DIMC * DIMC / 4) / 256, 256, 0, stream>>>(W, Wbf);
    pack_c_kernel<<<dim3(NPROT / 32, DIMC / 32), dim3(32, 8), 0, stream>>>(C, CTbf);
    cn_kernel<<<dim3((NPROT + 255) / 256, DIMC / 128), 256, 0, stream>>>(C, cn);

    gemm_kernel<true><<<dim3(MROWS / 128, DIMC / 128), 256, 0, stream>>>(
        Pbf, Wbf, bias, phibf, DIMC);
    rn_kernel<<<MROWS / 4, 256, 0, stream>>>(phibf, rn);
    gemm_kernel<false><<<dim3(MROWS / 128, NPAD / 128), 256, 0, stream>>>(
        phibf, CTbf, nullptr, fc, NPAD);
    top3_final_kernel<<<MROWS / 4, 256, 0, stream>>>(fc, cn, rn, out);
}